// Round 9
// baseline (233.598 us; speedup 1.0000x reference)
//
#include <hip/hip_runtime.h>
#include <hip/hip_bf16.h>
#include <math.h>

typedef __bf16 bf16;
typedef bf16 bf16x4 __attribute__((ext_vector_type(4)));
typedef bf16 bf16x8 __attribute__((ext_vector_type(8)));
typedef float f32x4 __attribute__((ext_vector_type(4)));

#define NNODES 16384
#define NB 64
#define HDIM 256
#define NHEADS 8
#define HD 32
#define GN_STRIPS 16

typedef __attribute__((address_space(3))) unsigned int lds_u32;
typedef __attribute__((address_space(1))) const unsigned int glb_u32;

// async 16B global->LDS (validated r6-r8). LDS dest = wave-uniform base + lane*16.
__device__ __forceinline__ void async_copy16(const bf16* gsrc, bf16* ldst) {
    __builtin_amdgcn_global_load_lds((glb_u32*)gsrc, (lds_u32*)ldst, 16, 0, 0);
}

// ---------- setup: meta (block 0) + all weights -> bf16, one launch ----------
__global__ void cvt_all(const float* __restrict__ pw_q, const float* __restrict__ pw_o,
                        const float* __restrict__ pw_1, const float* __restrict__ pw_2,
                        bf16* __restrict__ dq, bf16* __restrict__ d_o,
                        bf16* __restrict__ d1, bf16* __restrict__ d2,
                        const int* __restrict__ batch, int* __restrict__ starts,
                        int* __restrict__ counts) {
    if (blockIdx.x == 0 && threadIdx.x < 64) {
        int b = threadIdx.x;
        int lo = 0, hi = NNODES;
        while (lo < hi) { int mid = (lo + hi) >> 1; if (batch[mid] < b) lo = mid + 1; else hi = mid; }
        int s0 = lo;
        lo = 0; hi = NNODES;
        while (lo < hi) { int mid = (lo + hi) >> 1; if (batch[mid] < b + 1) lo = mid + 1; else hi = mid; }
        starts[b] = s0;
        counts[b] = lo - s0;
    }
    int i = blockIdx.x * 256 + threadIdx.x;
    const float* src; bf16* dst; int j;
    if (i < 49152)       { src = pw_q; dst = dq;  j = i; }
    else if (i < 65536)  { src = pw_o; dst = d_o; j = i - 49152; }
    else if (i < 131072) { src = pw_1; dst = d1;  j = i - 65536; }
    else                 { src = pw_2; dst = d2;  j = i - 131072; }
    float4 v = *(const float4*)(src + (size_t)j * 4);
    bf16x4 o;
    o[0] = (bf16)v.x; o[1] = (bf16)v.y; o[2] = (bf16)v.z; o[3] = (bf16)v.w;
    *(bf16x4*)(dst + (size_t)j * 4) = o;
}

// ---------- GraphNorm phase 1: per-(graph,strip,feature) partial sum/sumsq ----------
__global__ __launch_bounds__(256) void gn_partial(
    const float* __restrict__ x, const int* __restrict__ starts,
    const int* __restrict__ counts, float* __restrict__ part) {
    int g = blockIdx.x, strip = blockIdx.y, hh = threadIdx.x;
    int s = starts[g], c = counts[g];
    int chunk = (c + GN_STRIPS - 1) / GN_STRIPS;
    int r0 = strip * chunk, r1 = min(c, r0 + chunk);
    float sum = 0.f, sq = 0.f;
    for (int r = r0; r < r1; ++r) {
        float v = x[(size_t)(s + r) * HDIM + hh];
        sum += v; sq += v * v;
    }
    part[((size_t)(g * GN_STRIPS + strip) * 2 + 0) * HDIM + hh] = sum;
    part[((size_t)(g * GN_STRIPS + strip) * 2 + 1) * HDIM + hh] = sq;
}

// ---------- GraphNorm phase 2: finalize to per-(g,h) affine ----------
__global__ __launch_bounds__(256) void gn_final(
    const float* __restrict__ part, const int* __restrict__ counts,
    const float* __restrict__ w, const float* __restrict__ b, float* __restrict__ stats) {
    int g = blockIdx.x, hh = threadIdx.x;
    float sum = 0.f, sq = 0.f;
    for (int st = 0; st < GN_STRIPS; ++st) {
        sum += part[((size_t)(g * GN_STRIPS + st) * 2 + 0) * HDIM + hh];
        sq  += part[((size_t)(g * GN_STRIPS + st) * 2 + 1) * HDIM + hh];
    }
    float cf = (float)counts[g];
    float mean = sum / cf;
    float var = (sq - cf * mean * mean) / fmaxf(cf - 1.f, 1.f);
    var = fmaxf(var, 0.f);
    float inv = 1.f / (sqrtf(var) + 1e-5f);
    float a = w[hh] * inv;
    stats[(size_t)g * 512 + hh] = a;
    stats[(size_t)g * 512 + 256 + hh] = b[hh] - mean * a;
}

// ---------- GraphNorm phase 3: apply ----------
__global__ __launch_bounds__(256) void gn_apply(
    const float* __restrict__ x, const int* __restrict__ batch,
    const float* __restrict__ stats, bf16* __restrict__ out) {
    size_t i = ((size_t)blockIdx.x * 256 + threadIdx.x) * 4;
    int row = (int)(i >> 8);
    int g = batch[row];
    int hh = (int)(i & 255);
    float4 xv = *(const float4*)(x + i);
    float4 av = *(const float4*)(stats + (size_t)g * 512 + hh);
    float4 bv = *(const float4*)(stats + (size_t)g * 512 + 256 + hh);
    bf16x4 o;
    o[0] = (bf16)(av.x * xv.x + bv.x);
    o[1] = (bf16)(av.y * xv.y + bv.y);
    o[2] = (bf16)(av.z * xv.z + bv.z);
    o[3] = (bf16)(av.w * xv.w + bv.w);
    *(bf16x4*)(out + i) = o;
}

// ---------- TN bf16 MFMA GEMM 128x128, BK=32 linear LDS (r6 layout) + 2-phase dbuf ----------
// Catalog minimum-2-phase: STAGE(t+1 into buf^1) -> compute(buf) -> one barrier.
// Loads for t+1 are in flight across the whole MFMA phase of t (T3-lite).
// MODE 0: store bf16. MODE 1: f32 + residual. MODE 2: exact GELU -> bf16.
template <int MODE>
__global__ __launch_bounds__(256) void gemm_tn(
    const bf16* __restrict__ A, const bf16* __restrict__ B,
    const float* __restrict__ bias, const float* __restrict__ res,
    void* __restrict__ Cout, int M, int N, int K) {
    __shared__ __align__(16) bf16 As[2][128 * 32];
    __shared__ __align__(16) bf16 Bs[2][128 * 32];
    const int row0 = blockIdx.x * 128;
    const int col0 = blockIdx.y * 128;
    const int tid = threadIdx.x;
    const int lane = tid & 63;
    const int wave = tid >> 6;
    const int wm = (wave >> 1) * 64;
    const int wn = (wave & 1) * 64;
    const int lr = lane & 15;
    const int lk = lane >> 4;
    const int c0 = tid;
    const int c1 = tid + 256;
    const int r0c = c0 >> 2, o0 = (c0 & 3) * 8;
    const int r1c = c1 >> 2, o1 = (c1 & 3) * 8;

    const bf16* Ab = A + (size_t)row0 * K;
    const bf16* Bb = B + (size_t)col0 * K;

    f32x4 acc[4][4] = {};

    auto stage = [&](int buf, int k0) {
        async_copy16(Ab + (size_t)r0c * K + k0 + o0, &As[buf][c0 * 8]);
        async_copy16(Ab + (size_t)r1c * K + k0 + o1, &As[buf][c1 * 8]);
        async_copy16(Bb + (size_t)r0c * K + k0 + o0, &Bs[buf][c0 * 8]);
        async_copy16(Bb + (size_t)r1c * K + k0 + o1, &Bs[buf][c1 * 8]);
    };

    const int nk = K >> 5;
    stage(0, 0);
    __syncthreads();  // vmcnt(0) drain: buf0 ready
    for (int t = 0; t < nk; ++t) {
        const int cur = t & 1;
        if (t + 1 < nk) stage(cur ^ 1, (t + 1) << 5);  // in flight during MFMA below
        bf16x8 af[4], bfr[4];
#pragma unroll
        for (int mi = 0; mi < 4; ++mi)
            af[mi] = *(const bf16x8*)&As[cur][(wm + mi * 16 + lr) * 32 + lk * 8];
#pragma unroll
        for (int ni = 0; ni < 4; ++ni)
            bfr[ni] = *(const bf16x8*)&Bs[cur][(wn + ni * 16 + lr) * 32 + lk * 8];
#pragma unroll
        for (int mi = 0; mi < 4; ++mi)
#pragma unroll
            for (int ni = 0; ni < 4; ++ni)
                acc[mi][ni] = __builtin_amdgcn_mfma_f32_16x16x32_bf16(af[mi], bfr[ni], acc[mi][ni], 0, 0, 0);
        __syncthreads();  // drains stage(t+1) vmcnt + protects buf reuse
    }

#pragma unroll
    for (int mi = 0; mi < 4; ++mi) {
#pragma unroll
        for (int ni = 0; ni < 4; ++ni) {
            const int col = col0 + wn + ni * 16 + lr;
            const float bv = bias[col];
#pragma unroll
            for (int r = 0; r < 4; ++r) {
                const int row = row0 + wm + mi * 16 + lk * 4 + r;
                float v = acc[mi][ni][r] + bv;
                size_t idx = (size_t)row * N + col;
                if (MODE == 0) {
                    ((bf16*)Cout)[idx] = (bf16)v;
                } else if (MODE == 1) {
                    ((float*)Cout)[idx] = v + res[idx];
                } else {
                    float gel = 0.5f * v * (1.f + erff(v * 0.70710678118654752f));
                    ((bf16*)Cout)[idx] = (bf16)gel;
                }
            }
        }
    }
}

// ---------- 64x64 MODE1 GEMM (out_proj, FFN2), BK=32 linear + 2-phase dbuf ----------
__global__ __launch_bounds__(256) void gemm_small_res(
    const bf16* __restrict__ A, const bf16* __restrict__ B,
    const float* __restrict__ bias, const float* __restrict__ res,
    float* __restrict__ Cout, int M, int N, int K) {
    __shared__ __align__(16) bf16 As[2][64 * 32];
    __shared__ __align__(16) bf16 Bs[2][64 * 32];
    const int row0 = blockIdx.x * 64;
    const int col0 = blockIdx.y * 64;
    const int tid = threadIdx.x;
    const int lane = tid & 63;
    const int wave = tid >> 6;
    const int wr = (wave >> 1) * 32;
    const int wc = (wave & 1) * 32;
    const int lr = lane & 15;
    const int lk = lane >> 4;
    const int rs = tid >> 2, os = (tid & 3) * 8;

    const bf16* Ab = A + (size_t)row0 * K;
    const bf16* Bb = B + (size_t)col0 * K;

    f32x4 acc[2][2] = {};

    auto stage = [&](int buf, int k0) {
        async_copy16(Ab + (size_t)rs * K + k0 + os, &As[buf][tid * 8]);
        async_copy16(Bb + (size_t)rs * K + k0 + os, &Bs[buf][tid * 8]);
    };

    const int nk = K >> 5;
    stage(0, 0);
    __syncthreads();
    for (int t = 0; t < nk; ++t) {
        const int cur = t & 1;
        if (t + 1 < nk) stage(cur ^ 1, (t + 1) << 5);
        bf16x8 af[2], bfr[2];
#pragma unroll
        for (int mi = 0; mi < 2; ++mi)
            af[mi] = *(const bf16x8*)&As[cur][(wr + mi * 16 + lr) * 32 + lk * 8];
#pragma unroll
        for (int ni = 0; ni < 2; ++ni)
            bfr[ni] = *(const bf16x8*)&Bs[cur][(wc + ni * 16 + lr) * 32 + lk * 8];
#pragma unroll
        for (int mi = 0; mi < 2; ++mi)
#pragma unroll
            for (int ni = 0; ni < 2; ++ni)
                acc[mi][ni] = __builtin_amdgcn_mfma_f32_16x16x32_bf16(af[mi], bfr[ni], acc[mi][ni], 0, 0, 0);
        __syncthreads();
    }

#pragma unroll
    for (int mi = 0; mi < 2; ++mi) {
#pragma unroll
        for (int ni = 0; ni < 2; ++ni) {
            const int col = col0 + wc + ni * 16 + lr;
            const float bv = bias[col];
#pragma unroll
            for (int r = 0; r < 4; ++r) {
                const int row = row0 + wr + mi * 16 + lk * 4 + r;
                size_t idx = (size_t)row * N + col;
                Cout[idx] = acc[mi][ni][r] + bv + res[idx];
            }
        }
    }
}

// ---------- MFMA flash attention (validated r8): block = (graph, head, q-chunk) ----------
__global__ __launch_bounds__(256) void attn_mfma(
    const bf16* __restrict__ qkv, const int* __restrict__ starts,
    const int* __restrict__ counts, bf16* __restrict__ ctx) {
    int g = blockIdx.x, h = blockIdx.y, qc = blockIdx.z;
    int s = starts[g], c = counts[g];
    if (qc * 256 >= c) return;
    __shared__ __align__(16) bf16 Qs[256][40];
    __shared__ __align__(16) bf16 Ks[64][40];
    __shared__ __align__(16) bf16 Vt[32][72];
    __shared__ __align__(16) bf16 Ps[4][64][72];
    __shared__ float Ls[4][64];
    const int tid = threadIdx.x;
    const int w = tid >> 6, lane = tid & 63;
    const int lo = lane & 15, hi = lane >> 4;
    const float scale = 0.17677669529663687f;  // 1/sqrt(32)
    const int nkt = (c + 63) >> 6;

    {
        int qrow = qc * 256 + tid;
        const bf16* qp = qkv + (size_t)(s + qrow) * 768 + h * HD;
#pragma unroll
        for (int t4 = 0; t4 < 4; ++t4) {
            bf16x8 sv;
            if (qrow < c) {
                bf16x8 v = *(const bf16x8*)(qp + t4 * 8);
#pragma unroll
                for (int u = 0; u < 8; ++u) sv[u] = (bf16)((float)v[u] * scale);
            } else {
#pragma unroll
                for (int u = 0; u < 8; ++u) sv[u] = (bf16)0.f;
            }
            *(bf16x8*)&Qs[tid][t4 * 8] = sv;
        }
    }
    __syncthreads();
    bf16x8 bq[4];
#pragma unroll
    for (int nt = 0; nt < 4; ++nt) bq[nt] = *(const bf16x8*)&Qs[w * 64 + nt * 16 + lo][hi * 8];

    f32x4 ctxa[4][2] = {};
    float l[4] = {0.f, 0.f, 0.f, 0.f};

    for (int kt = 0; kt < nkt; ++kt) {
        {
            int krow = kt * 64 + (tid >> 2);
            bf16x8 v;
            if (krow < c) v = *(const bf16x8*)(qkv + (size_t)(s + krow) * 768 + 256 + h * HD + (tid & 3) * 8);
            else {
#pragma unroll
                for (int u = 0; u < 8; ++u) v[u] = (bf16)0.f;
            }
            *(bf16x8*)&Ks[tid >> 2][(tid & 3) * 8] = v;
        }
        {
            int vrow = kt * 64 + (tid & 63);
            int dg = tid >> 6;
            bf16x8 v;
            if (vrow < c) v = *(const bf16x8*)(qkv + (size_t)(s + vrow) * 768 + 512 + h * HD + dg * 8);
            else {
#pragma unroll
                for (int u = 0; u < 8; ++u) v[u] = (bf16)0.f;
            }
#pragma unroll
            for (int u = 0; u < 8; ++u) Vt[dg * 8 + u][tid & 63] = v[u];
        }
        __syncthreads();

        f32x4 sacc[4][4] = {};
#pragma unroll
        for (int kmt = 0; kmt < 4; ++kmt) {
            bf16x8 ak = *(const bf16x8*)&Ks[kmt * 16 + lo][hi * 8];
#pragma unroll
            for (int nt = 0; nt < 4; ++nt)
                sacc[kmt][nt] = __builtin_amdgcn_mfma_f32_16x16x32_bf16(ak, bq[nt], sacc[kmt][nt], 0, 0, 0);
        }
#pragma unroll
        for (int kmt = 0; kmt < 4; ++kmt) {
            int kbase = kt * 64 + kmt * 16 + hi * 4;
#pragma unroll
            for (int nt = 0; nt < 4; ++nt) {
                bf16x4 pv;
#pragma unroll
                for (int r = 0; r < 4; ++r) {
                    float p = (kbase + r < c) ? __expf(sacc[kmt][nt][r]) : 0.f;
                    l[nt] += p;
                    pv[r] = (bf16)p;
                }
                *(bf16x4*)&Ps[w][nt * 16 + lo][kmt * 16 + hi * 4] = pv;
            }
        }
#pragma unroll
        for (int ks = 0; ks < 2; ++ks) {
            bf16x8 bv[2];
#pragma unroll
            for (int dn = 0; dn < 2; ++dn) bv[dn] = *(const bf16x8*)&Vt[dn * 16 + lo][ks * 32 + hi * 8];
#pragma unroll
            for (int qmt = 0; qmt < 4; ++qmt) {
                bf16x8 ap = *(const bf16x8*)&Ps[w][qmt * 16 + lo][ks * 32 + hi * 8];
#pragma unroll
                for (int dn = 0; dn < 2; ++dn)
                    ctxa[qmt][dn] = __builtin_amdgcn_mfma_f32_16x16x32_bf16(ap, bv[dn], ctxa[qmt][dn], 0, 0, 0);
            }
        }
        __syncthreads();
    }

#pragma unroll
    for (int nt = 0; nt < 4; ++nt) {
        l[nt] += __shfl_xor(l[nt], 16);
        l[nt] += __shfl_xor(l[nt], 32);
    }
    if (hi == 0) {
#pragma unroll
        for (int nt = 0; nt < 4; ++nt) Ls[w][nt * 16 + lo] = l[nt];
    }
#pragma unroll
    for (int qmt = 0; qmt < 4; ++qmt) {
#pragma unroll
        for (int r = 0; r < 4; ++r) {
            int qrow = qc * 256 + w * 64 + qmt * 16 + hi * 4 + r;
            if (qrow < c) {
                float linv = 1.f / Ls[w][qmt * 16 + hi * 4 + r];
                bf16* op = ctx + (size_t)(s + qrow) * HDIM + h * HD;
#pragma unroll
                for (int dn = 0; dn < 2; ++dn)
                    op[dn * 16 + lo] = (bf16)(ctxa[qmt][dn][r] * linv);
            }
        }
    }
}

extern "C" void kernel_launch(void* const* d_in, const int* in_sizes, int n_in,
                              void* d_out, int out_size, void* d_ws, size_t ws_size,
                              hipStream_t stream) {
    const float* x        = (const float*)d_in[0];
    const int*   batch    = (const int*)d_in[1];
    const float* norm1_w  = (const float*)d_in[3];
    const float* norm1_b  = (const float*)d_in[4];
    const float* in_proj_w  = (const float*)d_in[5];
    const float* in_proj_b  = (const float*)d_in[6];
    const float* out_proj_w = (const float*)d_in[7];
    const float* out_proj_b = (const float*)d_in[8];
    const float* norm2_w  = (const float*)d_in[9];
    const float* norm2_b  = (const float*)d_in[10];
    const float* ffn_w1   = (const float*)d_in[11];
    const float* ffn_b1   = (const float*)d_in[12];
    const float* ffn_w2   = (const float*)d_in[13];
    const float* ffn_b2   = (const float*)d_in[14];
    float* out = (float*)d_out;

    char* ws = (char*)d_ws;
    size_t off = 0;
    auto alloc = [&](size_t bytes) -> void* {
        void* p = ws + off;
        off += bytes;
        off = (off + 255) & ~(size_t)255;
        return p;
    };
    int*  starts = (int*)alloc(NB * 4);
    int*  counts = (int*)alloc(NB * 4);
    bf16* wq = (bf16*)alloc((size_t)768 * 256 * 2);
    bf16* wo = (bf16*)alloc((size_t)256 * 256 * 2);
    bf16* w1 = (bf16*)alloc((size_t)1024 * 256 * 2);
    bf16* w2 = (bf16*)alloc((size_t)256 * 1024 * 2);
    bf16* t0  = (bf16*)alloc((size_t)NNODES * HDIM * 2);   // xn1 -> ctx -> xn2
    bf16* qkv = (bf16*)alloc((size_t)NNODES * 768 * 2);
    float* y  = (float*)alloc((size_t)NNODES * HDIM * 4);  // x + attn_out
    bf16* hbuf = (bf16*)alloc((size_t)NNODES * 1024 * 2);  // gelu(ffn1)
    float* gnpart = (float*)alloc((size_t)NB * GN_STRIPS * 2 * HDIM * 4);
    float* gnstats = (float*)alloc((size_t)NB * 512 * 4);

    // 1. setup: meta + all weights -> bf16
    cvt_all<<<196608 / 256, 256, 0, stream>>>(in_proj_w, out_proj_w, ffn_w1, ffn_w2,
                                              wq, wo, w1, w2, batch, starts, counts);
    // 2. GraphNorm1: x -> t0 (bf16)
    gn_partial<<<dim3(NB, GN_STRIPS), 256, 0, stream>>>(x, starts, counts, gnpart);
    gn_final<<<NB, 256, 0, stream>>>(gnpart, counts, norm1_w, norm1_b, gnstats);
    gn_apply<<<NNODES * HDIM / 1024, 256, 0, stream>>>(x, batch, gnstats, t0);
    // 3. QKV: t0 @ wq^T + b -> qkv (bf16) [16384, 768]
    gemm_tn<0><<<dim3(NNODES / 128, 768 / 128), 256, 0, stream>>>(
        t0, wq, in_proj_b, nullptr, qkv, NNODES, 768, 256);
    // 4. MFMA attention -> t0 (ctx, bf16); q-chunks parallel in z
    attn_mfma<<<dim3(NB, NHEADS, 2), 256, 0, stream>>>(qkv, starts, counts, t0);
    // 5. out_proj + residual(x) -> y (f32)
    gemm_small_res<<<dim3(NNODES / 64, 256 / 64), 256, 0, stream>>>(
        t0, wo, out_proj_b, x, y, NNODES, 256, 256);
    // 6. GraphNorm2: y -> t0 (bf16)
    gn_partial<<<dim3(NB, GN_STRIPS), 256, 0, stream>>>(y, starts, counts, gnpart);
    gn_final<<<NB, 256, 0, stream>>>(gnpart, counts, norm2_w, norm2_b, gnstats);
    gn_apply<<<NNODES * HDIM / 1024, 256, 0, stream>>>(y, batch, gnstats, t0);
    // 7. FFN1 + exact GELU -> hbuf (bf16) [16384, 1024]
    gemm_tn<2><<<dim3(NNODES / 128, 1024 / 128), 256, 0, stream>>>(
        t0, w1, ffn_b1, nullptr, hbuf, NNODES, 1024, 256);
    // 8. FFN2 + residual(y) -> out (f32)
    gemm_small_res<<<dim3(NNODES / 64, 256 / 64), 256, 0, stream>>>(
        hbuf, w2, ffn_b2, y, out, NNODES, 256, 1024);
}

// Round 10
// 230.934 us; speedup vs baseline: 1.0115x; 1.0115x over previous
//
#include <hip/hip_runtime.h>
#include <hip/hip_bf16.h>
#include <math.h>

typedef __bf16 bf16;
typedef bf16 bf16x4 __attribute__((ext_vector_type(4)));
typedef bf16 bf16x8 __attribute__((ext_vector_type(8)));
typedef float f32x4 __attribute__((ext_vector_type(4)));

#define NNODES 16384
#define NB 64
#define HDIM 256
#define NHEADS 8
#define HD 32
#define GN_STRIPS 16

typedef __attribute__((address_space(3))) unsigned int lds_u32;
typedef __attribute__((address_space(1))) const unsigned int glb_u32;

// async 16B global->LDS (validated r6-r9). LDS dest = wave-uniform base + lane*16.
__device__ __forceinline__ void async_copy16(const bf16* gsrc, bf16* ldst) {
    __builtin_amdgcn_global_load_lds((glb_u32*)gsrc, (lds_u32*)ldst, 16, 0, 0);
}

// ---------- setup: meta (block 0) + all weights -> bf16, one launch ----------
__global__ void cvt_all(const float* __restrict__ pw_q, const float* __restrict__ pw_o,
                        const float* __restrict__ pw_1, const float* __restrict__ pw_2,
                        bf16* __restrict__ dq, bf16* __restrict__ d_o,
                        bf16* __restrict__ d1, bf16* __restrict__ d2,
                        const int* __restrict__ batch, int* __restrict__ starts,
                        int* __restrict__ counts) {
    if (blockIdx.x == 0 && threadIdx.x < 64) {
        int b = threadIdx.x;
        int lo = 0, hi = NNODES;
        while (lo < hi) { int mid = (lo + hi) >> 1; if (batch[mid] < b) lo = mid + 1; else hi = mid; }
        int s0 = lo;
        lo = 0; hi = NNODES;
        while (lo < hi) { int mid = (lo + hi) >> 1; if (batch[mid] < b + 1) lo = mid + 1; else hi = mid; }
        starts[b] = s0;
        counts[b] = lo - s0;
    }
    int i = blockIdx.x * 256 + threadIdx.x;
    const float* src; bf16* dst; int j;
    if (i < 49152)       { src = pw_q; dst = dq;  j = i; }
    else if (i < 65536)  { src = pw_o; dst = d_o; j = i - 49152; }
    else if (i < 131072) { src = pw_1; dst = d1;  j = i - 65536; }
    else                 { src = pw_2; dst = d2;  j = i - 131072; }
    float4 v = *(const float4*)(src + (size_t)j * 4);
    bf16x4 o;
    o[0] = (bf16)v.x; o[1] = (bf16)v.y; o[2] = (bf16)v.z; o[3] = (bf16)v.w;
    *(bf16x4*)(dst + (size_t)j * 4) = o;
}

// ---------- GraphNorm phase 1: per-(graph,strip,feature) partial sum/sumsq ----------
__global__ __launch_bounds__(256) void gn_partial(
    const float* __restrict__ x, const int* __restrict__ starts,
    const int* __restrict__ counts, float* __restrict__ part) {
    int g = blockIdx.x, strip = blockIdx.y, hh = threadIdx.x;
    int s = starts[g], c = counts[g];
    int chunk = (c + GN_STRIPS - 1) / GN_STRIPS;
    int r0 = strip * chunk, r1 = min(c, r0 + chunk);
    float sum = 0.f, sq = 0.f;
    for (int r = r0; r < r1; ++r) {
        float v = x[(size_t)(s + r) * HDIM + hh];
        sum += v; sq += v * v;
    }
    part[((size_t)(g * GN_STRIPS + strip) * 2 + 0) * HDIM + hh] = sum;
    part[((size_t)(g * GN_STRIPS + strip) * 2 + 1) * HDIM + hh] = sq;
}

// ---------- GraphNorm phase 2: finalize to per-(g,h) affine ----------
__global__ __launch_bounds__(256) void gn_final(
    const float* __restrict__ part, const int* __restrict__ counts,
    const float* __restrict__ w, const float* __restrict__ b, float* __restrict__ stats) {
    int g = blockIdx.x, hh = threadIdx.x;
    float sum = 0.f, sq = 0.f;
    for (int st = 0; st < GN_STRIPS; ++st) {
        sum += part[((size_t)(g * GN_STRIPS + st) * 2 + 0) * HDIM + hh];
        sq  += part[((size_t)(g * GN_STRIPS + st) * 2 + 1) * HDIM + hh];
    }
    float cf = (float)counts[g];
    float mean = sum / cf;
    float var = (sq - cf * mean * mean) / fmaxf(cf - 1.f, 1.f);
    var = fmaxf(var, 0.f);
    float inv = 1.f / (sqrtf(var) + 1e-5f);
    float a = w[hh] * inv;
    stats[(size_t)g * 512 + hh] = a;
    stats[(size_t)g * 512 + 256 + hh] = b[hh] - mean * a;
}

// ---------- GraphNorm phase 3: apply ----------
__global__ __launch_bounds__(256) void gn_apply(
    const float* __restrict__ x, const int* __restrict__ batch,
    const float* __restrict__ stats, bf16* __restrict__ out) {
    size_t i = ((size_t)blockIdx.x * 256 + threadIdx.x) * 4;
    int row = (int)(i >> 8);
    int g = batch[row];
    int hh = (int)(i & 255);
    float4 xv = *(const float4*)(x + i);
    float4 av = *(const float4*)(stats + (size_t)g * 512 + hh);
    float4 bv = *(const float4*)(stats + (size_t)g * 512 + 256 + hh);
    bf16x4 o;
    o[0] = (bf16)(av.x * xv.x + bv.x);
    o[1] = (bf16)(av.y * xv.y + bv.y);
    o[2] = (bf16)(av.z * xv.z + bv.z);
    o[3] = (bf16)(av.w * xv.w + bv.w);
    *(bf16x4*)(out + i) = o;
}

// ---------- 64x128 TN GEMM for wide-N (QKV, FFN1): 6-8 blocks/CU ----------
// r8 counters showed 128x128 at 25% occupancy / MfmaUtil 5.5% -> latency-bound,
// grid-limited (768 blocks). BM=64 doubles/quadruples blocks/CU. Single-buffer
// BK=32 linear LDS (r6-validated). 4 waves: each 64 rows x 32-col slice, A-frags
// broadcast across waves. MODE 0: bf16 store. MODE 2: exact GELU -> bf16.
template <int MODE>
__global__ __launch_bounds__(256) void gemm_tn64(
    const bf16* __restrict__ A, const bf16* __restrict__ B,
    const float* __restrict__ bias, void* __restrict__ Cout,
    int M, int N, int K) {
    __shared__ __align__(16) bf16 As[64 * 32];
    __shared__ __align__(16) bf16 Bs[128 * 32];
    const int row0 = blockIdx.x * 64;
    const int col0 = blockIdx.y * 128;
    const int tid = threadIdx.x;
    const int lane = tid & 63;
    const int wave = tid >> 6;
    const int wn = wave * 32;
    const int lr = lane & 15;
    const int lk = lane >> 4;
    const int ra = tid >> 2, oa = (tid & 3) * 8;

    const bf16* Ab = A + (size_t)row0 * K;
    const bf16* Bb = B + (size_t)col0 * K;

    f32x4 acc[4][2] = {};

    for (int k0 = 0; k0 < K; k0 += 32) {
        __syncthreads();
        async_copy16(Ab + (size_t)ra * K + k0 + oa, &As[tid * 8]);
        async_copy16(Bb + (size_t)ra * K + k0 + oa, &Bs[tid * 8]);
        async_copy16(Bb + (size_t)(ra + 64) * K + k0 + oa, &Bs[(tid + 256) * 8]);
        __syncthreads();
        bf16x8 af[4], bfr[2];
#pragma unroll
        for (int mi = 0; mi < 4; ++mi)
            af[mi] = *(const bf16x8*)&As[(mi * 16 + lr) * 32 + lk * 8];
#pragma unroll
        for (int ni = 0; ni < 2; ++ni)
            bfr[ni] = *(const bf16x8*)&Bs[(wn + ni * 16 + lr) * 32 + lk * 8];
#pragma unroll
        for (int mi = 0; mi < 4; ++mi)
#pragma unroll
            for (int ni = 0; ni < 2; ++ni)
                acc[mi][ni] = __builtin_amdgcn_mfma_f32_16x16x32_bf16(af[mi], bfr[ni], acc[mi][ni], 0, 0, 0);
    }

#pragma unroll
    for (int mi = 0; mi < 4; ++mi) {
#pragma unroll
        for (int ni = 0; ni < 2; ++ni) {
            const int col = col0 + wn + ni * 16 + lr;
            const float bv = bias[col];
#pragma unroll
            for (int r = 0; r < 4; ++r) {
                const int row = row0 + mi * 16 + lk * 4 + r;
                float v = acc[mi][ni][r] + bv;
                size_t idx = (size_t)row * N + col;
                if (MODE == 0) {
                    ((bf16*)Cout)[idx] = (bf16)v;
                } else {
                    float gel = 0.5f * v * (1.f + erff(v * 0.70710678118654752f));
                    ((bf16*)Cout)[idx] = (bf16)gel;
                }
            }
        }
    }
}

// ---------- 64x64 MODE1 GEMM (out_proj, FFN2) — r7-validated single-buffer ----------
__global__ __launch_bounds__(256) void gemm_small_res(
    const bf16* __restrict__ A, const bf16* __restrict__ B,
    const float* __restrict__ bias, const float* __restrict__ res,
    float* __restrict__ Cout, int M, int N, int K) {
    __shared__ __align__(16) bf16 As[64 * 32];
    __shared__ __align__(16) bf16 Bs[64 * 32];
    const int row0 = blockIdx.x * 64;
    const int col0 = blockIdx.y * 64;
    const int tid = threadIdx.x;
    const int lane = tid & 63;
    const int wave = tid >> 6;
    const int wr = (wave >> 1) * 32;
    const int wc = (wave & 1) * 32;
    const int lr = lane & 15;
    const int lk = lane >> 4;
    const int rs = tid >> 2, os = (tid & 3) * 8;

    const bf16* Ab = A + (size_t)row0 * K;
    const bf16* Bb = B + (size_t)col0 * K;

    f32x4 acc[2][2] = {};

    for (int k0 = 0; k0 < K; k0 += 32) {
        __syncthreads();
        async_copy16(Ab + (size_t)rs * K + k0 + os, &As[tid * 8]);
        async_copy16(Bb + (size_t)rs * K + k0 + os, &Bs[tid * 8]);
        __syncthreads();
        bf16x8 af[2], bfr[2];
#pragma unroll
        for (int mi = 0; mi < 2; ++mi)
            af[mi] = *(const bf16x8*)&As[(wr + mi * 16 + lr) * 32 + lk * 8];
#pragma unroll
        for (int ni = 0; ni < 2; ++ni)
            bfr[ni] = *(const bf16x8*)&Bs[(wc + ni * 16 + lr) * 32 + lk * 8];
#pragma unroll
        for (int mi = 0; mi < 2; ++mi)
#pragma unroll
            for (int ni = 0; ni < 2; ++ni)
                acc[mi][ni] = __builtin_amdgcn_mfma_f32_16x16x32_bf16(af[mi], bfr[ni], acc[mi][ni], 0, 0, 0);
    }

#pragma unroll
    for (int mi = 0; mi < 2; ++mi) {
#pragma unroll
        for (int ni = 0; ni < 2; ++ni) {
            const int col = col0 + wc + ni * 16 + lr;
            const float bv = bias[col];
#pragma unroll
            for (int r = 0; r < 4; ++r) {
                const int row = row0 + wr + mi * 16 + lk * 4 + r;
                size_t idx = (size_t)row * N + col;
                Cout[idx] = acc[mi][ni][r] + bv + res[idx];
            }
        }
    }
}

// ---------- MFMA flash attention (validated r8): block = (graph, head, q-chunk) ----------
__global__ __launch_bounds__(256) void attn_mfma(
    const bf16* __restrict__ qkv, const int* __restrict__ starts,
    const int* __restrict__ counts, bf16* __restrict__ ctx) {
    int g = blockIdx.x, h = blockIdx.y, qc = blockIdx.z;
    int s = starts[g], c = counts[g];
    if (qc * 256 >= c) return;
    __shared__ __align__(16) bf16 Qs[256][40];
    __shared__ __align__(16) bf16 Ks[64][40];
    __shared__ __align__(16) bf16 Vt[32][72];
    __shared__ __align__(16) bf16 Ps[4][64][72];
    __shared__ float Ls[4][64];
    const int tid = threadIdx.x;
    const int w = tid >> 6, lane = tid & 63;
    const int lo = lane & 15, hi = lane >> 4;
    const float scale = 0.17677669529663687f;  // 1/sqrt(32)
    const int nkt = (c + 63) >> 6;

    {
        int qrow = qc * 256 + tid;
        const bf16* qp = qkv + (size_t)(s + qrow) * 768 + h * HD;
#pragma unroll
        for (int t4 = 0; t4 < 4; ++t4) {
            bf16x8 sv;
            if (qrow < c) {
                bf16x8 v = *(const bf16x8*)(qp + t4 * 8);
#pragma unroll
                for (int u = 0; u < 8; ++u) sv[u] = (bf16)((float)v[u] * scale);
            } else {
#pragma unroll
                for (int u = 0; u < 8; ++u) sv[u] = (bf16)0.f;
            }
            *(bf16x8*)&Qs[tid][t4 * 8] = sv;
        }
    }
    __syncthreads();
    bf16x8 bq[4];
#pragma unroll
    for (int nt = 0; nt < 4; ++nt) bq[nt] = *(const bf16x8*)&Qs[w * 64 + nt * 16 + lo][hi * 8];

    f32x4 ctxa[4][2] = {};
    float l[4] = {0.f, 0.f, 0.f, 0.f};

    for (int kt = 0; kt < nkt; ++kt) {
        {
            int krow = kt * 64 + (tid >> 2);
            bf16x8 v;
            if (krow < c) v = *(const bf16x8*)(qkv + (size_t)(s + krow) * 768 + 256 + h * HD + (tid & 3) * 8);
            else {
#pragma unroll
                for (int u = 0; u < 8; ++u) v[u] = (bf16)0.f;
            }
            *(bf16x8*)&Ks[tid >> 2][(tid & 3) * 8] = v;
        }
        {
            int vrow = kt * 64 + (tid & 63);
            int dg = tid >> 6;
            bf16x8 v;
            if (vrow < c) v = *(const bf16x8*)(qkv + (size_t)(s + vrow) * 768 + 512 + h * HD + dg * 8);
            else {
#pragma unroll
                for (int u = 0; u < 8; ++u) v[u] = (bf16)0.f;
            }
#pragma unroll
            for (int u = 0; u < 8; ++u) Vt[dg * 8 + u][tid & 63] = v[u];
        }
        __syncthreads();

        f32x4 sacc[4][4] = {};
#pragma unroll
        for (int kmt = 0; kmt < 4; ++kmt) {
            bf16x8 ak = *(const bf16x8*)&Ks[kmt * 16 + lo][hi * 8];
#pragma unroll
            for (int nt = 0; nt < 4; ++nt)
                sacc[kmt][nt] = __builtin_amdgcn_mfma_f32_16x16x32_bf16(ak, bq[nt], sacc[kmt][nt], 0, 0, 0);
        }
#pragma unroll
        for (int kmt = 0; kmt < 4; ++kmt) {
            int kbase = kt * 64 + kmt * 16 + hi * 4;
#pragma unroll
            for (int nt = 0; nt < 4; ++nt) {
                bf16x4 pv;
#pragma unroll
                for (int r = 0; r < 4; ++r) {
                    float p = (kbase + r < c) ? __expf(sacc[kmt][nt][r]) : 0.f;
                    l[nt] += p;
                    pv[r] = (bf16)p;
                }
                *(bf16x4*)&Ps[w][nt * 16 + lo][kmt * 16 + hi * 4] = pv;
            }
        }
#pragma unroll
        for (int ks = 0; ks < 2; ++ks) {
            bf16x8 bv[2];
#pragma unroll
            for (int dn = 0; dn < 2; ++dn) bv[dn] = *(const bf16x8*)&Vt[dn * 16 + lo][ks * 32 + hi * 8];
#pragma unroll
            for (int qmt = 0; qmt < 4; ++qmt) {
                bf16x8 ap = *(const bf16x8*)&Ps[w][qmt * 16 + lo][ks * 32 + hi * 8];
#pragma unroll
                for (int dn = 0; dn < 2; ++dn)
                    ctxa[qmt][dn] = __builtin_amdgcn_mfma_f32_16x16x32_bf16(ap, bv[dn], ctxa[qmt][dn], 0, 0, 0);
            }
        }
        __syncthreads();
    }

#pragma unroll
    for (int nt = 0; nt < 4; ++nt) {
        l[nt] += __shfl_xor(l[nt], 16);
        l[nt] += __shfl_xor(l[nt], 32);
    }
    if (hi == 0) {
#pragma unroll
        for (int nt = 0; nt < 4; ++nt) Ls[w][nt * 16 + lo] = l[nt];
    }
#pragma unroll
    for (int qmt = 0; qmt < 4; ++qmt) {
#pragma unroll
        for (int r = 0; r < 4; ++r) {
            int qrow = qc * 256 + w * 64 + qmt * 16 + hi * 4 + r;
            if (qrow < c) {
                float linv = 1.f / Ls[w][qmt * 16 + hi * 4 + r];
                bf16* op = ctx + (size_t)(s + qrow) * HDIM + h * HD;
#pragma unroll
                for (int dn = 0; dn < 2; ++dn)
                    op[dn * 16 + lo] = (bf16)(ctxa[qmt][dn][r] * linv);
            }
        }
    }
}

extern "C" void kernel_launch(void* const* d_in, const int* in_sizes, int n_in,
                              void* d_out, int out_size, void* d_ws, size_t ws_size,
                              hipStream_t stream) {
    const float* x        = (const float*)d_in[0];
    const int*   batch    = (const int*)d_in[1];
    const float* norm1_w  = (const float*)d_in[3];
    const float* norm1_b  = (const float*)d_in[4];
    const float* in_proj_w  = (const float*)d_in[5];
    const float* in_proj_b  = (const float*)d_in[6];
    const float* out_proj_w = (const float*)d_in[7];
    const float* out_proj_b = (const float*)d_in[8];
    const float* norm2_w  = (const float*)d_in[9];
    const float* norm2_b  = (const float*)d_in[10];
    const float* ffn_w1   = (const float*)d_in[11];
    const float* ffn_b1   = (const float*)d_in[12];
    const float* ffn_w2   = (const float*)d_in[13];
    const float* ffn_b2   = (const float*)d_in[14];
    float* out = (float*)d_out;

    char* ws = (char*)d_ws;
    size_t off = 0;
    auto alloc = [&](size_t bytes) -> void* {
        void* p = ws + off;
        off += bytes;
        off = (off + 255) & ~(size_t)255;
        return p;
    };
    int*  starts = (int*)alloc(NB * 4);
    int*  counts = (int*)alloc(NB * 4);
    bf16* wq = (bf16*)alloc((size_t)768 * 256 * 2);
    bf16* wo = (bf16*)alloc((size_t)256 * 256 * 2);
    bf16* w1 = (bf16*)alloc((size_t)1024 * 256 * 2);
    bf16* w2 = (bf16*)alloc((size_t)256 * 1024 * 2);
    bf16* t0  = (bf16*)alloc((size_t)NNODES * HDIM * 2);   // xn1 -> ctx -> xn2
    bf16* qkv = (bf16*)alloc((size_t)NNODES * 768 * 2);
    float* y  = (float*)alloc((size_t)NNODES * HDIM * 4);  // x + attn_out
    bf16* hbuf = (bf16*)alloc((size_t)NNODES * 1024 * 2);  // gelu(ffn1)
    float* gnpart = (float*)alloc((size_t)NB * GN_STRIPS * 2 * HDIM * 4);
    float* gnstats = (float*)alloc((size_t)NB * 512 * 4);

    // 1. setup: meta + all weights -> bf16
    cvt_all<<<196608 / 256, 256, 0, stream>>>(in_proj_w, out_proj_w, ffn_w1, ffn_w2,
                                              wq, wo, w1, w2, batch, starts, counts);
    // 2. GraphNorm1: x -> t0 (bf16)
    gn_partial<<<dim3(NB, GN_STRIPS), 256, 0, stream>>>(x, starts, counts, gnpart);
    gn_final<<<NB, 256, 0, stream>>>(gnpart, counts, norm1_w, norm1_b, gnstats);
    gn_apply<<<NNODES * HDIM / 1024, 256, 0, stream>>>(x, batch, gnstats, t0);
    // 3. QKV: t0 @ wq^T + b -> qkv (bf16) [16384, 768]  (64x128 tiles, 1536 blocks)
    gemm_tn64<0><<<dim3(NNODES / 64, 768 / 128), 256, 0, stream>>>(
        t0, wq, in_proj_b, qkv, NNODES, 768, 256);
    // 4. MFMA attention -> t0 (ctx, bf16); q-chunks parallel in z
    attn_mfma<<<dim3(NB, NHEADS, 2), 256, 0, stream>>>(qkv, starts, counts, t0);
    // 5. out_proj + residual(x) -> y (f32)
    gemm_small_res<<<dim3(NNODES / 64, 256 / 64), 256, 0, stream>>>(
        t0, wo, out_proj_b, x, y, NNODES, 256, 256);
    // 6. GraphNorm2: y -> t0 (bf16)
    gn_partial<<<dim3(NB, GN_STRIPS), 256, 0, stream>>>(y, starts, counts, gnpart);
    gn_final<<<NB, 256, 0, stream>>>(gnpart, counts, norm2_w, norm2_b, gnstats);
    gn_apply<<<NNODES * HDIM / 1024, 256, 0, stream>>>(y, batch, gnstats, t0);
    // 7. FFN1 + exact GELU -> hbuf (bf16) [16384, 1024]  (64x128 tiles, 2048 blocks)
    gemm_tn64<2><<<dim3(NNODES / 64, 1024 / 128), 256, 0, stream>>>(
        t0, w1, ffn_b1, hbuf, NNODES, 1024, 256);
    // 8. FFN2 + residual(y) -> out (f32)
    gemm_small_res<<<dim3(NNODES / 64, 256 / 64), 256, 0, stream>>>(
        hbuf, w2, ffn_b2, y, out, NNODES, 256, 1024);
}

// Round 11
// 222.949 us; speedup vs baseline: 1.0478x; 1.0358x over previous
//
#include <hip/hip_runtime.h>
#include <hip/hip_bf16.h>
#include <math.h>

typedef __bf16 bf16;
typedef bf16 bf16x4 __attribute__((ext_vector_type(4)));
typedef bf16 bf16x8 __attribute__((ext_vector_type(8)));
typedef float f32x4 __attribute__((ext_vector_type(4)));

#define NNODES 16384
#define NB 64
#define HDIM 256
#define NHEADS 8
#define HD 32
#define GN_STRIPS 16

typedef __attribute__((address_space(3))) unsigned int lds_u32;
typedef __attribute__((address_space(1))) const unsigned int glb_u32;

// async 16B global->LDS (validated r6-r10). LDS dest = wave-uniform base + lane*16.
__device__ __forceinline__ void async_copy16(const bf16* gsrc, bf16* ldst) {
    __builtin_amdgcn_global_load_lds((glb_u32*)gsrc, (lds_u32*)ldst, 16, 0, 0);
}

// ---------- setup: weights->bf16 (blocks 0..767) + meta + zero gstats (768..775) ----------
// gstats: [gsum1 | gsq1 | gsum2 | gsq2], each 64*256 floats = 65536 floats total.
__global__ void cvt_all(const float* __restrict__ pw_q, const float* __restrict__ pw_o,
                        const float* __restrict__ pw_1, const float* __restrict__ pw_2,
                        bf16* __restrict__ dq, bf16* __restrict__ d_o,
                        bf16* __restrict__ d1, bf16* __restrict__ d2,
                        const int* __restrict__ batch, int* __restrict__ starts,
                        int* __restrict__ counts, float* __restrict__ gstats) {
    if (blockIdx.x >= 768) {
        int zb = blockIdx.x - 768;
        float4 z = {0.f, 0.f, 0.f, 0.f};
        float4* p = (float4*)gstats + (size_t)zb * 2048 + threadIdx.x;
#pragma unroll
        for (int j = 0; j < 8; ++j) p[j * 256] = z;
        if (blockIdx.x == 768 && threadIdx.x < 64) {
            int b = threadIdx.x;
            int lo = 0, hi = NNODES;
            while (lo < hi) { int mid = (lo + hi) >> 1; if (batch[mid] < b) lo = mid + 1; else hi = mid; }
            int s0 = lo;
            lo = 0; hi = NNODES;
            while (lo < hi) { int mid = (lo + hi) >> 1; if (batch[mid] < b + 1) lo = mid + 1; else hi = mid; }
            starts[b] = s0;
            counts[b] = lo - s0;
        }
        return;
    }
    int i = blockIdx.x * 256 + threadIdx.x;
    const float* src; bf16* dst; int j;
    if (i < 49152)       { src = pw_q; dst = dq;  j = i; }
    else if (i < 65536)  { src = pw_o; dst = d_o; j = i - 49152; }
    else if (i < 131072) { src = pw_1; dst = d1;  j = i - 65536; }
    else                 { src = pw_2; dst = d2;  j = i - 131072; }
    float4 v = *(const float4*)(src + (size_t)j * 4);
    bf16x4 o;
    o[0] = (bf16)v.x; o[1] = (bf16)v.y; o[2] = (bf16)v.z; o[3] = (bf16)v.w;
    *(bf16x4*)(dst + (size_t)j * 4) = o;
}

// ---------- GraphNorm partial: atomicAdd per-(g,h) sums (<=16 adds/cell) ----------
__global__ __launch_bounds__(256) void gn_partial(
    const float* __restrict__ x, const int* __restrict__ starts,
    const int* __restrict__ counts, float* __restrict__ gsum, float* __restrict__ gsq) {
    int g = blockIdx.x, strip = blockIdx.y, hh = threadIdx.x;
    int s = starts[g], c = counts[g];
    int chunk = (c + GN_STRIPS - 1) / GN_STRIPS;
    int r0 = strip * chunk, r1 = min(c, r0 + chunk);
    float sum = 0.f, sq = 0.f;
    for (int r = r0; r < r1; ++r) {
        float v = x[(size_t)(s + r) * HDIM + hh];
        sum += v; sq += v * v;
    }
    if (r1 > r0) {
        atomicAdd(&gsum[g * HDIM + hh], sum);
        atomicAdd(&gsq[g * HDIM + hh], sq);
    }
}

// ---------- GraphNorm apply (final folded in): per-thread stats from L2 ----------
__global__ __launch_bounds__(256) void gn_apply(
    const float* __restrict__ x, const int* __restrict__ batch,
    const float* __restrict__ gsum, const float* __restrict__ gsq,
    const int* __restrict__ counts, const float* __restrict__ w,
    const float* __restrict__ b, bf16* __restrict__ out) {
    size_t i = ((size_t)blockIdx.x * 256 + threadIdx.x) * 4;
    int row = (int)(i >> 8);
    int g = batch[row];
    int hh = (int)(i & 255);
    float cf = (float)counts[g];
    float inv_c = 1.f / cf;
    float inv_c1 = 1.f / fmaxf(cf - 1.f, 1.f);
    float4 sv = *(const float4*)(gsum + g * HDIM + hh);
    float4 qv = *(const float4*)(gsq + g * HDIM + hh);
    float4 xv = *(const float4*)(x + i);
    float4 wv = *(const float4*)(w + hh);
    float4 bv = *(const float4*)(b + hh);
    bf16x4 o;
#define GN_ONE(S, Q, X, W, B, IDX)                                          \
    {                                                                       \
        float mean = (S) * inv_c;                                           \
        float var = fmaxf(((Q) - cf * mean * mean) * inv_c1, 0.f);          \
        float a = (W) / (sqrtf(var) + 1e-5f);                               \
        o[IDX] = (bf16)(a * ((X) - mean) + (B));                            \
    }
    GN_ONE(sv.x, qv.x, xv.x, wv.x, bv.x, 0)
    GN_ONE(sv.y, qv.y, xv.y, wv.y, bv.y, 1)
    GN_ONE(sv.z, qv.z, xv.z, wv.z, bv.z, 2)
    GN_ONE(sv.w, qv.w, xv.w, wv.w, bv.w, 3)
#undef GN_ONE
    *(bf16x4*)(out + i) = o;
}

// ---------- 64x128 TN GEMM (QKV, FFN1) — r10 structure ----------
template <int MODE>
__global__ __launch_bounds__(256) void gemm_tn64(
    const bf16* __restrict__ A, const bf16* __restrict__ B,
    const float* __restrict__ bias, void* __restrict__ Cout,
    int M, int N, int K) {
    __shared__ __align__(16) bf16 As[64 * 32];
    __shared__ __align__(16) bf16 Bs[128 * 32];
    const int row0 = blockIdx.x * 64;
    const int col0 = blockIdx.y * 128;
    const int tid = threadIdx.x;
    const int lane = tid & 63;
    const int wave = tid >> 6;
    const int wn = wave * 32;
    const int lr = lane & 15;
    const int lk = lane >> 4;
    const int ra = tid >> 2, oa = (tid & 3) * 8;

    const bf16* Ab = A + (size_t)row0 * K;
    const bf16* Bb = B + (size_t)col0 * K;

    f32x4 acc[4][2] = {};

    for (int k0 = 0; k0 < K; k0 += 32) {
        __syncthreads();
        async_copy16(Ab + (size_t)ra * K + k0 + oa, &As[tid * 8]);
        async_copy16(Bb + (size_t)ra * K + k0 + oa, &Bs[tid * 8]);
        async_copy16(Bb + (size_t)(ra + 64) * K + k0 + oa, &Bs[(tid + 256) * 8]);
        __syncthreads();
        bf16x8 af[4], bfr[2];
#pragma unroll
        for (int mi = 0; mi < 4; ++mi)
            af[mi] = *(const bf16x8*)&As[(mi * 16 + lr) * 32 + lk * 8];
#pragma unroll
        for (int ni = 0; ni < 2; ++ni)
            bfr[ni] = *(const bf16x8*)&Bs[(wn + ni * 16 + lr) * 32 + lk * 8];
#pragma unroll
        for (int mi = 0; mi < 4; ++mi)
#pragma unroll
            for (int ni = 0; ni < 2; ++ni)
                acc[mi][ni] = __builtin_amdgcn_mfma_f32_16x16x32_bf16(af[mi], bfr[ni], acc[mi][ni], 0, 0, 0);
    }

#pragma unroll
    for (int mi = 0; mi < 4; ++mi) {
#pragma unroll
        for (int ni = 0; ni < 2; ++ni) {
            const int col = col0 + wn + ni * 16 + lr;
            const float bv = bias[col];
#pragma unroll
            for (int r = 0; r < 4; ++r) {
                const int row = row0 + mi * 16 + lk * 4 + r;
                float v = acc[mi][ni][r] + bv;
                size_t idx = (size_t)row * N + col;
                if (MODE == 0) {
                    ((bf16*)Cout)[idx] = (bf16)v;
                } else {
                    float gel = 0.5f * v * (1.f + erff(v * 0.70710678118654752f));
                    ((bf16*)Cout)[idx] = (bf16)gel;
                }
            }
        }
    }
}

// ---------- 64x64 MODE1 GEMM (out_proj, FFN2) — r7/r10-validated ----------
__global__ __launch_bounds__(256) void gemm_small_res(
    const bf16* __restrict__ A, const bf16* __restrict__ B,
    const float* __restrict__ bias, const float* __restrict__ res,
    float* __restrict__ Cout, int M, int N, int K) {
    __shared__ __align__(16) bf16 As[64 * 32];
    __shared__ __align__(16) bf16 Bs[64 * 32];
    const int row0 = blockIdx.x * 64;
    const int col0 = blockIdx.y * 64;
    const int tid = threadIdx.x;
    const int lane = tid & 63;
    const int wave = tid >> 6;
    const int wr = (wave >> 1) * 32;
    const int wc = (wave & 1) * 32;
    const int lr = lane & 15;
    const int lk = lane >> 4;
    const int rs = tid >> 2, os = (tid & 3) * 8;

    const bf16* Ab = A + (size_t)row0 * K;
    const bf16* Bb = B + (size_t)col0 * K;

    f32x4 acc[2][2] = {};

    for (int k0 = 0; k0 < K; k0 += 32) {
        __syncthreads();
        async_copy16(Ab + (size_t)rs * K + k0 + os, &As[tid * 8]);
        async_copy16(Bb + (size_t)rs * K + k0 + os, &Bs[tid * 8]);
        __syncthreads();
        bf16x8 af[2], bfr[2];
#pragma unroll
        for (int mi = 0; mi < 2; ++mi)
            af[mi] = *(const bf16x8*)&As[(wr + mi * 16 + lr) * 32 + lk * 8];
#pragma unroll
        for (int ni = 0; ni < 2; ++ni)
            bfr[ni] = *(const bf16x8*)&Bs[(wc + ni * 16 + lr) * 32 + lk * 8];
#pragma unroll
        for (int mi = 0; mi < 2; ++mi)
#pragma unroll
            for (int ni = 0; ni < 2; ++ni)
                acc[mi][ni] = __builtin_amdgcn_mfma_f32_16x16x32_bf16(af[mi], bfr[ni], acc[mi][ni], 0, 0, 0);
    }

#pragma unroll
    for (int mi = 0; mi < 2; ++mi) {
#pragma unroll
        for (int ni = 0; ni < 2; ++ni) {
            const int col = col0 + wc + ni * 16 + lr;
            const float bv = bias[col];
#pragma unroll
            for (int r = 0; r < 4; ++r) {
                const int row = row0 + wr + mi * 16 + lk * 4 + r;
                size_t idx = (size_t)row * N + col;
                Cout[idx] = acc[mi][ni][r] + bv + res[idx];
            }
        }
    }
}

// ---------- MFMA flash attention: block = (graph, head, q-chunk) ----------
// z=0 (full 256-q chunks): r8-validated q-split path. Tail chunks (<=64 live rows):
// "slim" k-split — each wave processes every 4th K-tile for the SAME 64 q rows
// (no-max softmax => disjoint-key partials just add), K/V frags straight from L2,
// no k-loop barriers; one merge barrier at the end (Ps reused as f32 scratch).
__global__ __launch_bounds__(256) void attn_mfma(
    const bf16* __restrict__ qkv, const int* __restrict__ starts,
    const int* __restrict__ counts, bf16* __restrict__ ctx) {
    int g = blockIdx.x, h = blockIdx.y, qc = blockIdx.z;
    int s = starts[g], c = counts[g];
    if (qc * 256 >= c) return;
    __shared__ __align__(16) bf16 Qs[256][40];
    __shared__ __align__(16) bf16 Ks[64][40];
    __shared__ __align__(16) bf16 Vt[32][72];
    __shared__ __align__(16) bf16 Ps[4][64][72];
    __shared__ float Ls[4][64];
    const int tid = threadIdx.x;
    const int w = tid >> 6, lane = tid & 63;
    const int lo = lane & 15, hi = lane >> 4;
    const float scale = 0.17677669529663687f;  // 1/sqrt(32)
    const int nkt = (c + 63) >> 6;
    const int rem = c - qc * 256;

    if (rem <= 64) {
        // ================= slim tail path =================
        {   // stage the 64 q rows: thread t -> row t>>2, col8 (t&3)*8
            int qr = (tid >> 2);
            int qrow = qc * 256 + qr;
            bf16x8 sv;
            if (qrow < c) {
                bf16x8 v = *(const bf16x8*)(qkv + (size_t)(s + qrow) * 768 + h * HD + (tid & 3) * 8);
#pragma unroll
                for (int u = 0; u < 8; ++u) sv[u] = (bf16)((float)v[u] * scale);
            } else {
#pragma unroll
                for (int u = 0; u < 8; ++u) sv[u] = (bf16)0.f;
            }
            *(bf16x8*)&Qs[qr][(tid & 3) * 8] = sv;
        }
        __syncthreads();
        bf16x8 bq[4];
#pragma unroll
        for (int nt = 0; nt < 4; ++nt) bq[nt] = *(const bf16x8*)&Qs[nt * 16 + lo][hi * 8];

        f32x4 ctxa[4][2] = {};
        float l[4] = {0.f, 0.f, 0.f, 0.f};

        for (int kt = w; kt < nkt; kt += 4) {
            // QK^T with register K-frags (L2-resident)
            f32x4 sacc[4][4] = {};
#pragma unroll
            for (int kmt = 0; kmt < 4; ++kmt) {
                int krow = kt * 64 + kmt * 16 + lo;
                bf16x8 ak;
                if (krow < c) ak = *(const bf16x8*)(qkv + (size_t)(s + krow) * 768 + 256 + h * HD + hi * 8);
                else {
#pragma unroll
                    for (int u = 0; u < 8; ++u) ak[u] = (bf16)0.f;
                }
#pragma unroll
                for (int nt = 0; nt < 4; ++nt)
                    sacc[kmt][nt] = __builtin_amdgcn_mfma_f32_16x16x32_bf16(ak, bq[nt], sacc[kmt][nt], 0, 0, 0);
            }
            // exp + l + P (per-wave Ps region)
#pragma unroll
            for (int kmt = 0; kmt < 4; ++kmt) {
                int kbase = kt * 64 + kmt * 16 + hi * 4;
#pragma unroll
                for (int nt = 0; nt < 4; ++nt) {
                    bf16x4 pv;
#pragma unroll
                    for (int r = 0; r < 4; ++r) {
                        float p = (kbase + r < c) ? __expf(sacc[kmt][nt][r]) : 0.f;
                        l[nt] += p;
                        pv[r] = (bf16)p;
                    }
                    *(bf16x4*)&Ps[w][nt * 16 + lo][kmt * 16 + hi * 4] = pv;
                }
            }
            // PV with register V-frags
#pragma unroll
            for (int ks = 0; ks < 2; ++ks) {
                bf16x8 bv[2];
#pragma unroll
                for (int dn = 0; dn < 2; ++dn) {
#pragma unroll
                    for (int u = 0; u < 8; ++u) {
                        int vrow = kt * 64 + ks * 32 + hi * 8 + u;
                        bv[dn][u] = (vrow < c)
                            ? qkv[(size_t)(s + vrow) * 768 + 512 + h * HD + dn * 16 + lo]
                            : (bf16)0.f;
                    }
                }
#pragma unroll
                for (int qmt = 0; qmt < 4; ++qmt) {
                    bf16x8 ap = *(const bf16x8*)&Ps[w][qmt * 16 + lo][ks * 32 + hi * 8];
#pragma unroll
                    for (int dn = 0; dn < 2; ++dn)
                        ctxa[qmt][dn] = __builtin_amdgcn_mfma_f32_16x16x32_bf16(ap, bv[dn], ctxa[qmt][dn], 0, 0, 0);
                }
            }
        }

        // wave-local l reduce, publish partials, merge across waves
#pragma unroll
        for (int nt = 0; nt < 4; ++nt) {
            l[nt] += __shfl_xor(l[nt], 16);
            l[nt] += __shfl_xor(l[nt], 32);
        }
        if (hi == 0) {
#pragma unroll
            for (int nt = 0; nt < 4; ++nt) Ls[w][nt * 16 + lo] = l[nt];
        }
        float* Fw = (float*)&Ps[w][0][0];  // 9216B/wave >= 64*32*4B
        __syncthreads();                   // Ps P-use done in all waves before f32 overwrite
#pragma unroll
        for (int qmt = 0; qmt < 4; ++qmt)
#pragma unroll
            for (int dn = 0; dn < 2; ++dn)
#pragma unroll
                for (int r = 0; r < 4; ++r)
                    Fw[(qmt * 16 + hi * 4 + r) * 32 + dn * 16 + lo] = ctxa[qmt][dn][r];
        __syncthreads();
        {
            int qr = tid >> 2;
            int qrow = qc * 256 + qr;
            if (qrow < c) {
                int d0 = (tid & 3) * 8;
                float lsum = Ls[0][qr] + Ls[1][qr] + Ls[2][qr] + Ls[3][qr];
                float linv = 1.f / lsum;
                const float* F0 = (const float*)&Ps[0][0][0];
                const float* F1 = (const float*)&Ps[1][0][0];
                const float* F2 = (const float*)&Ps[2][0][0];
                const float* F3 = (const float*)&Ps[3][0][0];
                bf16x8 o;
#pragma unroll
                for (int j = 0; j < 8; ++j) {
                    int idx = qr * 32 + d0 + j;
                    o[j] = (bf16)((F0[idx] + F1[idx] + F2[idx] + F3[idx]) * linv);
                }
                *(bf16x8*)(ctx + (size_t)(s + qrow) * HDIM + h * HD + d0) = o;
            }
        }
        return;
    }

    // ================= full-chunk path (r8-validated) =================
    {
        int qrow = qc * 256 + tid;
        const bf16* qp = qkv + (size_t)(s + qrow) * 768 + h * HD;
#pragma unroll
        for (int t4 = 0; t4 < 4; ++t4) {
            bf16x8 sv;
            if (qrow < c) {
                bf16x8 v = *(const bf16x8*)(qp + t4 * 8);
#pragma unroll
                for (int u = 0; u < 8; ++u) sv[u] = (bf16)((float)v[u] * scale);
            } else {
#pragma unroll
                for (int u = 0; u < 8; ++u) sv[u] = (bf16)0.f;
            }
            *(bf16x8*)&Qs[tid][t4 * 8] = sv;
        }
    }
    __syncthreads();
    bf16x8 bq[4];
#pragma unroll
    for (int nt = 0; nt < 4; ++nt) bq[nt] = *(const bf16x8*)&Qs[w * 64 + nt * 16 + lo][hi * 8];

    f32x4 ctxa[4][2] = {};
    float l[4] = {0.f, 0.f, 0.f, 0.f};

    for (int kt = 0; kt < nkt; ++kt) {
        {
            int krow = kt * 64 + (tid >> 2);
            bf16x8 v;
            if (krow < c) v = *(const bf16x8*)(qkv + (size_t)(s + krow) * 768 + 256 + h * HD + (tid & 3) * 8);
            else {
#pragma unroll
                for (int u = 0; u < 8; ++u) v[u] = (bf16)0.f;
            }
            *(bf16x8*)&Ks[tid >> 2][(tid & 3) * 8] = v;
        }
        {
            int vrow = kt * 64 + (tid & 63);
            int dg = tid >> 6;
            bf16x8 v;
            if (vrow < c) v = *(const bf16x8*)(qkv + (size_t)(s + vrow) * 768 + 512 + h * HD + dg * 8);
            else {
#pragma unroll
                for (int u = 0; u < 8; ++u) v[u] = (bf16)0.f;
            }
#pragma unroll
            for (int u = 0; u < 8; ++u) Vt[dg * 8 + u][tid & 63] = v[u];
        }
        __syncthreads();

        f32x4 sacc[4][4] = {};
#pragma unroll
        for (int kmt = 0; kmt < 4; ++kmt) {
            bf16x8 ak = *(const bf16x8*)&Ks[kmt * 16 + lo][hi * 8];
#pragma unroll
            for (int nt = 0; nt < 4; ++nt)
                sacc[kmt][nt] = __builtin_amdgcn_mfma_f32_16x16x32_bf16(ak, bq[nt], sacc[kmt][nt], 0, 0, 0);
        }
#pragma unroll
        for (int kmt = 0; kmt < 4; ++kmt) {
            int kbase = kt * 64 + kmt * 16 + hi * 4;
#pragma unroll
            for (int nt = 0; nt < 4; ++nt) {
                bf16x4 pv;
#pragma unroll
                for (int r = 0; r < 4; ++r) {
                    float p = (kbase + r < c) ? __expf(sacc[kmt][nt][r]) : 0.f;
                    l[nt] += p;
                    pv[r] = (bf16)p;
                }
                *(bf16x4*)&Ps[w][nt * 16 + lo][kmt * 16 + hi * 4] = pv;
            }
        }
#pragma unroll
        for (int ks = 0; ks < 2; ++ks) {
            bf16x8 bv[2];
#pragma unroll
            for (int dn = 0; dn < 2; ++dn) bv[dn] = *(const bf16x8*)&Vt[dn * 16 + lo][ks * 32 + hi * 8];
#pragma unroll
            for (int qmt = 0; qmt < 4; ++qmt) {
                bf16x8 ap = *(const bf16x8*)&Ps[w][qmt * 16 + lo][ks * 32 + hi * 8];
#pragma unroll
                for (int dn = 0; dn < 2; ++dn)
                    ctxa[qmt][dn] = __builtin_amdgcn_mfma_f32_16x16x32_bf16(ap, bv[dn], ctxa[qmt][dn], 0, 0, 0);
            }
        }
        __syncthreads();
    }

#pragma unroll
    for (int nt = 0; nt < 4; ++nt) {
        l[nt] += __shfl_xor(l[nt], 16);
        l[nt] += __shfl_xor(l[nt], 32);
    }
    if (hi == 0) {
#pragma unroll
        for (int nt = 0; nt < 4; ++nt) Ls[w][nt * 16 + lo] = l[nt];
    }
#pragma unroll
    for (int qmt = 0; qmt < 4; ++qmt) {
#pragma unroll
        for (int r = 0; r < 4; ++r) {
            int qrow = qc * 256 + w * 64 + qmt * 16 + hi * 4 + r;
            if (qrow < c) {
                float linv = 1.f / Ls[w][qmt * 16 + hi * 4 + r];
                bf16* op = ctx + (size_t)(s + qrow) * HDIM + h * HD;
#pragma unroll
                for (int dn = 0; dn < 2; ++dn)
                    op[dn * 16 + lo] = (bf16)(ctxa[qmt][dn][r] * linv);
            }
        }
    }
}

extern "C" void kernel_launch(void* const* d_in, const int* in_sizes, int n_in,
                              void* d_out, int out_size, void* d_ws, size_t ws_size,
                              hipStream_t stream) {
    const float* x        = (const float*)d_in[0];
    const int*   batch    = (const int*)d_in[1];
    const float* norm1_w  = (const float*)d_in[3];
    const float* norm1_b  = (const float*)d_in[4];
    const float* in_proj_w  = (const float*)d_in[5];
    const float* in_proj_b  = (const float*)d_in[6];
    const float* out_proj_w = (const float*)d_in[7];
    const float* out_proj_b = (const float*)d_in[8];
    const float* norm2_w  = (const float*)d_in[9];
    const float* norm2_b  = (const float*)d_in[10];
    const float* ffn_w1   = (const float*)d_in[11];
    const float* ffn_b1   = (const float*)d_in[12];
    const float* ffn_w2   = (const float*)d_in[13];
    const float* ffn_b2   = (const float*)d_in[14];
    float* out = (float*)d_out;

    char* ws = (char*)d_ws;
    size_t off = 0;
    auto alloc = [&](size_t bytes) -> void* {
        void* p = ws + off;
        off += bytes;
        off = (off + 255) & ~(size_t)255;
        return p;
    };
    int*  starts = (int*)alloc(NB * 4);
    int*  counts = (int*)alloc(NB * 4);
    bf16* wq = (bf16*)alloc((size_t)768 * 256 * 2);
    bf16* wo = (bf16*)alloc((size_t)256 * 256 * 2);
    bf16* w1 = (bf16*)alloc((size_t)1024 * 256 * 2);
    bf16* w2 = (bf16*)alloc((size_t)256 * 1024 * 2);
    bf16* t0  = (bf16*)alloc((size_t)NNODES * HDIM * 2);   // xn1 -> ctx -> xn2
    bf16* qkv = (bf16*)alloc((size_t)NNODES * 768 * 2);
    float* y  = (float*)alloc((size_t)NNODES * HDIM * 4);  // x + attn_out
    bf16* hbuf = (bf16*)alloc((size_t)NNODES * 1024 * 2);  // gelu(ffn1)
    float* gstats = (float*)alloc((size_t)4 * NB * HDIM * 4);  // gsum1|gsq1|gsum2|gsq2
    float* gsum1 = gstats;
    float* gsq1  = gstats + NB * HDIM;
    float* gsum2 = gstats + 2 * NB * HDIM;
    float* gsq2  = gstats + 3 * NB * HDIM;

    // 1. setup: weights->bf16 + meta + zero gstats
    cvt_all<<<776, 256, 0, stream>>>(in_proj_w, out_proj_w, ffn_w1, ffn_w2,
                                     wq, wo, w1, w2, batch, starts, counts, gstats);
    // 2-3. GraphNorm1: x -> t0 (bf16)
    gn_partial<<<dim3(NB, GN_STRIPS), 256, 0, stream>>>(x, starts, counts, gsum1, gsq1);
    gn_apply<<<NNODES * HDIM / 1024, 256, 0, stream>>>(x, batch, gsum1, gsq1, counts,
                                                       norm1_w, norm1_b, t0);
    // 4. QKV: t0 @ wq^T + b -> qkv (bf16) [16384, 768]
    gemm_tn64<0><<<dim3(NNODES / 64, 768 / 128), 256, 0, stream>>>(
        t0, wq, in_proj_b, qkv, NNODES, 768, 256);
    // 5. attention -> t0 (ctx, bf16); tail chunks use slim k-split path
    attn_mfma<<<dim3(NB, NHEADS, 2), 256, 0, stream>>>(qkv, starts, counts, t0);
    // 6. out_proj + residual(x) -> y (f32)
    gemm_small_res<<<dim3(NNODES / 64, 256 / 64), 256, 0, stream>>>(
        t0, wo, out_proj_b, x, y, NNODES, 256, 256);
    // 7-8. GraphNorm2: y -> t0 (bf16)
    gn_partial<<<dim3(NB, GN_STRIPS), 256, 0, stream>>>(y, starts, counts, gsum2, gsq2);
    gn_apply<<<NNODES * HDIM / 1024, 256, 0, stream>>>(y, batch, gsum2, gsq2, counts,
                                                       norm2_w, norm2_b, t0);
    // 9. FFN1 + exact GELU -> hbuf (bf16) [16384, 1024]
    gemm_tn64<2><<<dim3(NNODES / 64, 1024 / 128), 256, 0, stream>>>(
        t0, w1, ffn_b1, hbuf, NNODES, 1024, 256);
    // 10. FFN2 + residual(y) -> out (f32)
    gemm_small_res<<<dim3(NNODES / 64, 256 / 64), 256, 0, stream>>>(
        hbuf, w2, ffn_b2, y, out, NNODES, 256, 1024);
}